// Round 5
// baseline (336.036 us; speedup 1.0000x reference)
//
#include <hip/hip_runtime.h>

// Atom_embedding_MP: B=4, N=100000, K=16, D=6, C_IN=13, 3 layers.
// Round-7: ONE thread per point, k-outer over neighbor PAIRS, global-stream.
//  Evidence so far:
//   R3(102.7us): k-inner, 2t/pt, VGPR=60, real-VALU ~36% (reported 72% is
//     the gfx94x SIMD-16 formula counting 2x on SIMD-32).
//   R6(111.5us): LDS-resident inputs, same time -> per-layer L3 re-reads
//     are NOT the bottleneck (falsified R4/R5 theory).
//  Remaining theory: per-wave dependent stalls.  The d-unrolled k-inner
//  form needs 13 COLUMN-strided W1 scalars per d (52B stride -> 169
//  unbatchable s_load_dword per layer, lgkm waits in lockstep).  This
//  round flips the loops so ALL weight access is row-contiguous
//  (s_load_dwordx8-batchable) and neighbor features stream pair-by-pair
//  (3x float4 + 1x float2 per pair, ~470 cyc of independent FMA per 4
//  loads -> deep compiler prefetch).  1 thread/point also removes the
//  duplicated tail + shfl (total wave-instrs -10%, floor ~32us).
//  Occupancy will READ low (~15-20%): whole 6250-wave grid is resident.
//  - Sum_k lrelu(x) = .6*Sum x + .4*Sum |x|  (|x| is a free VOP modifier).

constexpr int DD  = 6;
constexpr int KK  = 16;
constexpr int CIN = 13;
constexpr float EPSV = 1e-5f;

__global__ __launch_bounds__(256) void atom_mp(
    const float* __restrict__ dist,   // [P, K]
    const float* __restrict__ at,     // [P, K, D]
    const float* __restrict__ W1,     // [3, CIN, CIN]
    const float* __restrict__ b1,     // [3, CIN]
    const float* __restrict__ W2,     // [3, CIN, D]
    const float* __restrict__ b2,     // [3, D]
    const float* __restrict__ gw,     // [3, D]
    const float* __restrict__ gb,     // [3, D]
    float* __restrict__ out,          // [P, D]
    int P)
{
    const int p = blockIdx.x * blockDim.x + threadIdx.x;
    if (p >= P) return;

    const float* __restrict__ ab = at   + (long)p * (KK * DD); // 384B-aligned
    const float* __restrict__ db = dist + (long)p * KK;        // 64B-aligned

    float pe[DD] = {1.f, 1.f, 1.f, 1.f, 1.f, 1.f};

    #pragma unroll 1   // keep the (large) layer body rolled: ~17KB fits I$
    for (int L = 0; L < 3; ++L) {
        const float* w1  = W1 + L * CIN * CIN;
        const float* w2  = W2 + L * CIN * DD;
        const float* bb1 = b1 + L * CIN;
        const float* bb2 = b2 + L * DD;
        const float* gwp = gw + L * DD;
        const float* gbp = gb + L * DD;

        // base[d] = b1[d] + pe @ W1[0:6, d]  -- row-contiguous weight reads
        float base[CIN];
        #pragma unroll
        for (int d = 0; d < CIN; ++d) base[d] = bb1[d];
        #pragma unroll
        for (int c = 0; c < DD; ++c) {
            const float pc = pe[c];
            #pragma unroll
            for (int d = 0; d < CIN; ++d)
                base[d] = fmaf(pc, w1[c * CIN + d], base[d]);
        }

        // hs1 = sum_k x, hs2 = sum_k |x|  over all 16 neighbors
        float hs1[CIN], hs2[CIN];
        #pragma unroll
        for (int d = 0; d < CIN; ++d) { hs1[d] = 0.f; hs2[d] = 0.f; }

        // neighbor PAIRS: 2x6 feats = 48B = 3 aligned float4; dists = float2
        #pragma unroll
        for (int kp = 0; kp < 8; ++kp) {
            const float4* fp4 =
                reinterpret_cast<const float4*>(ab + kp * 12);
            const float4 q0 = fp4[0];
            const float4 q1 = fp4[1];
            const float4 q2 = fp4[2];
            const float2 dd2 =
                *reinterpret_cast<const float2*>(db + 2 * kp);

            const float f0[6] = {q0.x, q0.y, q0.z, q0.w, q1.x, q1.y};
            const float f1[6] = {q1.z, q1.w, q2.x, q2.y, q2.z, q2.w};

            float x0[CIN], x1[CIN];
            #pragma unroll
            for (int d = 0; d < CIN; ++d) { x0[d] = base[d]; x1[d] = base[d]; }

            #pragma unroll
            for (int j = 0; j < 6; ++j) {
                const float a0 = f0[j], a1 = f1[j];
                const float* wr = w1 + (6 + j) * CIN;   // row-contiguous
                #pragma unroll
                for (int d = 0; d < CIN; ++d) {
                    const float w = wr[d];
                    x0[d] = fmaf(a0, w, x0[d]);
                    x1[d] = fmaf(a1, w, x1[d]);
                }
            }
            {
                const float* wr = w1 + 12 * CIN;
                #pragma unroll
                for (int d = 0; d < CIN; ++d) {
                    const float w = wr[d];
                    x0[d] = fmaf(dd2.x, w, x0[d]);
                    x1[d] = fmaf(dd2.y, w, x1[d]);
                }
            }
            #pragma unroll
            for (int d = 0; d < CIN; ++d) {
                hs1[d] += x0[d];
                hs2[d] += __builtin_fabsf(x0[d]);
                hs1[d] += x1[d];
                hs2[d] += __builtin_fabsf(x1[d]);
            }
        }

        // lrelu-after-sum:  hsum = .6*hs1 + .4*hs2
        float hsum[CIN];
        #pragma unroll
        for (int d = 0; d < CIN; ++d)
            hsum[d] = fmaf(0.6f, hs1[d], 0.4f * hs2[d]);

        // msg = hsum @ W2 + 16*b2   (row-contiguous W2 reads)
        float msg[DD];
        #pragma unroll
        for (int d = 0; d < DD; ++d) msg[d] = 16.f * bb2[d];
        #pragma unroll
        for (int c = 0; c < CIN; ++c) {
            const float hc = hsum[c];
            #pragma unroll
            for (int d = 0; d < DD; ++d)
                msg[d] = fmaf(hc, w2[c * DD + d], msg[d]);
        }

        // GroupNorm(2 groups of 3) + affine + lrelu, residual add
        #pragma unroll
        for (int g = 0; g < 2; ++g) {
            float m0 = msg[3 * g], m1 = msg[3 * g + 1], m2 = msg[3 * g + 2];
            float mu = (m0 + m1 + m2) * (1.f / 3.f);
            float d0 = m0 - mu, d1 = m1 - mu, d2 = m2 - mu;
            float var = (d0 * d0 + d1 * d1 + d2 * d2) * (1.f / 3.f);
            float rs = rsqrtf(var + EPSV);
            float dv[3] = {d0, d1, d2};
            #pragma unroll
            for (int c = 0; c < 3; ++c) {
                int ch = 3 * g + c;
                float xn = fmaf(dv[c] * rs, gwp[ch], gbp[ch]);
                pe[ch] = fmaf(0.6f, xn, pe[ch]);
                pe[ch] = fmaf(0.4f, __builtin_fabsf(xn), pe[ch]);
            }
        }
    }

    // 24B store, 8B-aligned for any p: 3x float2
    float* op = out + (long)p * DD;
    *reinterpret_cast<float2*>(op)     = make_float2(pe[0], pe[1]);
    *reinterpret_cast<float2*>(op + 2) = make_float2(pe[2], pe[3]);
    *reinterpret_cast<float2*>(op + 4) = make_float2(pe[4], pe[5]);
}

extern "C" void kernel_launch(void* const* d_in, const int* in_sizes, int n_in,
                              void* d_out, int out_size, void* d_ws, size_t ws_size,
                              hipStream_t stream) {
    const float* dist = (const float*)d_in[0];
    const float* at   = (const float*)d_in[1];
    const float* W1   = (const float*)d_in[2];
    const float* b1   = (const float*)d_in[3];
    const float* W2   = (const float*)d_in[4];
    const float* b2   = (const float*)d_in[5];
    const float* gw   = (const float*)d_in[6];
    const float* gb   = (const float*)d_in[7];
    float* out = (float*)d_out;

    int P = in_sizes[0] / KK;   // dist is [P, K]
    int threads = 256;
    int blocks = (P + threads - 1) / threads;
    atom_mp<<<blocks, threads, 0, stream>>>(dist, at, W1, b1, W2, b2, gw, gb, out, P);
}

// Round 6
// 279.667 us; speedup vs baseline: 1.2016x; 1.2016x over previous
//
#include <hip/hip_runtime.h>

// Atom_embedding_MP: B=4, N=100000, K=16, D=6, C_IN=13, 3 layers.
// Round-8: R3-best structure (102.7us control), ONE change: 512-thread blocks.
//  Evidence: best structure shows avg occupancy only ~11.5 waves/CU (36%)
//  despite VGPR=60 allowing 32/CU and 48 waves/CU of queued work; real
//  VALU busy ~36% (37.6us of VALU in 102.7us). LDS-staging (R6) and
//  per-wave ILP (R7) both falsified as levers. Remaining theory: machine
//  never fills -- workgroup concurrency ~ CP launch rate x block lifetime,
//  ~3 concurrent 4-wave blocks/CU. 512-thread blocks pack 8 waves per
//  dispatch slot -> 2x resident waves at identical code.
//  - 2 threads/point (8 neighbors each), inputs re-read per layer from L3
//    (proven not the bottleneck at this occupancy).
//  - loop order d->j->k: W1 weights batched by compiler into wide s_loads.
//  - lrelu-acc: sum += .6x + .4|x| (free |x| modifier).
//  - hsum[13] pair-reduced with __shfl_xor(.,1); tail redundant in pair.

constexpr int DD  = 6;
constexpr int KK  = 16;
constexpr int CIN = 13;
constexpr int TPB = 512;
constexpr float EPSV = 1e-5f;

__global__ __launch_bounds__(TPB) void atom_mp(
    const float* __restrict__ dist,   // [P, K]
    const float* __restrict__ at,     // [P, K, D]
    const float* __restrict__ W1,     // [3, CIN, CIN]
    const float* __restrict__ b1,     // [3, CIN]
    const float* __restrict__ W2,     // [3, CIN, D]
    const float* __restrict__ b2,     // [3, D]
    const float* __restrict__ gw,     // [3, D]
    const float* __restrict__ gb,     // [3, D]
    float* __restrict__ out,          // [P, D]
    int P)
{
    int t = blockIdx.x * TPB + threadIdx.x;
    int p = t >> 1;      // point index
    int h = t & 1;       // which half of the neighbors
    if (p >= P) return;

    // ---- register-resident input: 8 neighbors x 6 feats + 8 dists --------
    float a[8 * DD];   // 48 floats
    float dq[8];

    const float4* ap4 = reinterpret_cast<const float4*>(
        at + (long)p * (KK * DD) + h * (8 * DD));
    #pragma unroll
    for (int i = 0; i < 12; ++i) {
        float4 q = ap4[i];
        a[4 * i + 0] = q.x; a[4 * i + 1] = q.y;
        a[4 * i + 2] = q.z; a[4 * i + 3] = q.w;
    }
    const float4* dp4 = reinterpret_cast<const float4*>(
        dist + (long)p * KK + h * 8);
    #pragma unroll
    for (int i = 0; i < 2; ++i) {
        float4 q = dp4[i];
        dq[4 * i + 0] = q.x; dq[4 * i + 1] = q.y;
        dq[4 * i + 2] = q.z; dq[4 * i + 3] = q.w;
    }

    float pe[DD] = {1.f, 1.f, 1.f, 1.f, 1.f, 1.f};

    #pragma unroll 1   // keep body in I$; each layer body ~1.2k instrs
    for (int L = 0; L < 3; ++L) {
        const float* w1  = W1 + L * CIN * CIN;
        const float* w2  = W2 + L * CIN * DD;
        const float* bb1 = b1 + L * CIN;
        const float* bb2 = b2 + L * DD;
        const float* gwp = gw + L * DD;
        const float* gbp = gb + L * DD;

        float hsum[CIN];

        #pragma unroll
        for (int d = 0; d < CIN; ++d) {
            // base_d = b1[d] + pe @ W1[0:6, d]
            float s = bb1[d];
            #pragma unroll
            for (int c = 0; c < DD; ++c)
                s = fmaf(pe[c], w1[c * CIN + d], s);

            // acc[k] over 8 neighbors; init folded into the j=0 FMA
            float w0 = w1[6 * CIN + d];
            float acc[8];
            #pragma unroll
            for (int k = 0; k < 8; ++k)
                acc[k] = fmaf(a[6 * k + 0], w0, s);
            #pragma unroll
            for (int j = 1; j < 7; ++j) {
                float w = w1[(6 + j) * CIN + d];
                #pragma unroll
                for (int k = 0; k < 8; ++k) {
                    float fv = (j < 6) ? a[6 * k + j] : dq[k];
                    acc[k] = fmaf(fv, w, acc[k]);
                }
            }
            // sum_k lrelu(acc[k]) = sum_k 0.6*acc + 0.4*|acc|
            float hs = 0.f;
            #pragma unroll
            for (int k = 0; k < 8; ++k) {
                hs = fmaf(0.6f, acc[k], hs);
                hs = fmaf(0.4f, __builtin_fabsf(acc[k]), hs);
            }
            hsum[d] = hs;
        }

        // reduce the lane pair (lanes 2i, 2i+1 hold halves of point i)
        #pragma unroll
        for (int d = 0; d < CIN; ++d)
            hsum[d] += __shfl_xor(hsum[d], 1, 64);

        // msg = hsum @ W2 + 16*b2   (both lanes, redundantly)
        float msg[DD];
        #pragma unroll
        for (int d = 0; d < DD; ++d) {
            float m = 16.f * bb2[d];
            #pragma unroll
            for (int c = 0; c < CIN; ++c)
                m = fmaf(hsum[c], w2[c * DD + d], m);
            msg[d] = m;
        }

        // GroupNorm(2 groups of 3) + affine + lrelu, residual add
        #pragma unroll
        for (int g = 0; g < 2; ++g) {
            float m0 = msg[3 * g], m1 = msg[3 * g + 1], m2 = msg[3 * g + 2];
            float mu = (m0 + m1 + m2) * (1.f / 3.f);
            float d0 = m0 - mu, d1 = m1 - mu, d2 = m2 - mu;
            float var = (d0 * d0 + d1 * d1 + d2 * d2) * (1.f / 3.f);
            float rs = rsqrtf(var + EPSV);
            float dv[3] = {d0, d1, d2};
            #pragma unroll
            for (int c = 0; c < 3; ++c) {
                int ch = 3 * g + c;
                float xn = fmaf(dv[c] * rs, gwp[ch], gbp[ch]);
                pe[ch] = fmaf(0.6f, xn, pe[ch]);
                pe[ch] = fmaf(0.4f, __builtin_fabsf(xn), pe[ch]);
            }
        }
    }

    // both lanes hold identical pe; split the 6-float store across the pair
    float* op = out + (long)p * DD;
    if (h == 0) {
        *reinterpret_cast<float2*>(op)     = make_float2(pe[0], pe[1]);
        *reinterpret_cast<float2*>(op + 2) = make_float2(pe[2], pe[3]);
    } else {
        *reinterpret_cast<float2*>(op + 4) = make_float2(pe[4], pe[5]);
    }
}

extern "C" void kernel_launch(void* const* d_in, const int* in_sizes, int n_in,
                              void* d_out, int out_size, void* d_ws, size_t ws_size,
                              hipStream_t stream) {
    const float* dist = (const float*)d_in[0];
    const float* at   = (const float*)d_in[1];
    const float* W1   = (const float*)d_in[2];
    const float* b1   = (const float*)d_in[3];
    const float* W2   = (const float*)d_in[4];
    const float* b2   = (const float*)d_in[5];
    const float* gw   = (const float*)d_in[6];
    const float* gb   = (const float*)d_in[7];
    float* out = (float*)d_out;

    int P = in_sizes[0] / KK;   // dist is [P, K]
    long threads_total = 2L * P;
    int blocks = (int)((threads_total + TPB - 1) / TPB);
    atom_mp<<<blocks, TPB, 0, stream>>>(dist, at, W1, b1, W2, b2, gw, gb, out, P);
}